// Round 1
// baseline (179.890 us; speedup 1.0000x reference)
//
#include <hip/hip_runtime.h>

#define BB    128
#define JJ    17
#define YY    96
#define XX    72
#define YX    (YY * XX)          // 6912 floats per (b,j) tile per channel
#define N4    (YX / 4)           // 1728 float4s per tile per channel
#define NQ    (BB * JJ)          // 2176 tiles
#define NTOT  (NQ * YX)          // 15040512 elements per channel
#define HALF4 (N4 / 2)           // 864 float4s per half-tile
#define NU    (NQ * 2)           // 4352 work units (half-tiles)
#define UNI   3                  // uniform float4 iters/thread (3*256 = 768)
#define TAIL  (HALF4 - UNI*256)  // 96 remaining float4s (threads 0..95)

// Sum of squared diffs for one float4 pair at float4-index i within a q-tile.
// yy = (4i)/72 = i/18 ; xx = (i%18)*4. gt uses trunc-toward-zero (np int32 cast).
__device__ __forceinline__ float tile_term(float4 lx, float4 ly, int i,
                                           float cx, float cy) {
    const int yy = i / 18;                // magic-mul constant divide
    const int xx = (i - yy * 18) * 4;
    const float gy = (float)(int)((float)yy - cy);
    float s = 0.0f;
    #pragma unroll
    for (int k = 0; k < 4; ++k) {
        const float gx = (float)(int)((float)(xx + k) - cx);
        const float dx = (&lx.x)[k] - gx;
        s = fmaf(dx, dx, s);
        const float dy = (&ly.x)[k] - gy;
        s = fmaf(dy, dy, s);
    }
    return s;
}

// Stage 1: one block per HALF-tile (u = q*2 + h). Payload is ~7 float4s/thread
// (~28 VGPRs) so the kernel reaches 8 waves/SIMD and ~double the resident
// outstanding-load depth of the full-tile version. All loads issued up front.
__global__ __launch_bounds__(256) void regloss_partial_kernel(
    const float* __restrict__ loc,    // (2, B, J, Y, X)
    const float* __restrict__ cord,   // (2, J, B)
    const float* __restrict__ tw,     // (B, J, 1)
    float* __restrict__ partial)      // (NU,) in d_ws
{
    const int tid = threadIdx.x;
    const int u  = blockIdx.x;
    const int q  = u >> 1;            // tile in loc's flat (b,j) order
    const int h  = u & 1;             // which half of the YX range
    // faithful-reshape quirk: gt constants index cord as (j' = q>>7, b' = q&127)
    const int jj = q >> 7;
    const int bb = q & 127;

    const float cx = cord[jj * BB + bb];
    const float cy = cord[JJ * BB + jj * BB + bb];
    const float w  = tw[q];

    const float4* p0 = (const float4*)(loc + (size_t)q * YX) + h * HALF4;
    const float4* p1 = (const float4*)(loc + (size_t)NTOT + (size_t)q * YX) + h * HALF4;

    float4 lx[UNI + 1], ly[UNI + 1];
    #pragma unroll
    for (int k = 0; k < UNI; ++k) lx[k] = p0[tid + 256 * k];
    #pragma unroll
    for (int k = 0; k < UNI; ++k) ly[k] = p1[tid + 256 * k];
    const bool has_tail = tid < TAIL;
    if (has_tail) {
        lx[UNI] = p0[UNI * 256 + tid];
        ly[UNI] = p1[UNI * 256 + tid];
    }

    const int ibase = h * HALF4 + tid;   // global float4 index within the tile
    float acc = 0.0f;
    #pragma unroll
    for (int k = 0; k < UNI; ++k)
        acc += tile_term(lx[k], ly[k], ibase + 256 * k, cx, cy);
    if (has_tail)
        acc += tile_term(lx[UNI], ly[UNI], ibase + UNI * 256, cx, cy);

    // wave64 shuffle reduction
    #pragma unroll
    for (int off = 32; off > 0; off >>= 1)
        acc += __shfl_down(acc, off, 64);

    __shared__ float wsum[4];
    const int lane = tid & 63;
    const int wave = tid >> 6;
    if (lane == 0) wsum[wave] = acc;
    __syncthreads();

    if (tid == 0)   // w is uniform per block: apply w^2 once here
        partial[u] = (w * w) * (wsum[0] + wsum[1] + wsum[2] + wsum[3]);
}

// Stage 2: single block folds the 4352 partials, scales, stores the scalar.
__global__ __launch_bounds__(256) void regloss_final_kernel(
    const float* __restrict__ partial, float* __restrict__ out)
{
    float acc = 0.0f;
    for (int i = threadIdx.x; i < NU; i += 256)
        acc += partial[i];

    #pragma unroll
    for (int off = 32; off > 0; off >>= 1)
        acc += __shfl_down(acc, off, 64);

    __shared__ float wsum[4];
    const int lane = threadIdx.x & 63;
    const int wave = threadIdx.x >> 6;
    if (lane == 0) wsum[wave] = acc;
    __syncthreads();

    if (threadIdx.x == 0) {
        const float s = wsum[0] + wsum[1] + wsum[2] + wsum[3];
        out[0] = s * (0.5f / (float)NTOT);   // 0.5 / (J * B * YX)
    }
}

extern "C" void kernel_launch(void* const* d_in, const int* in_sizes, int n_in,
                              void* d_out, int out_size, void* d_ws, size_t ws_size,
                              hipStream_t stream) {
    const float* loc  = (const float*)d_in[0];   // (2,128,17,96,72) fp32
    const float* cord = (const float*)d_in[1];   // (2,17,128) fp32
    const float* tw   = (const float*)d_in[2];   // (128,17,1) fp32
    float* partial = (float*)d_ws;               // NU floats, overwritten each call
    float* out = (float*)d_out;

    regloss_partial_kernel<<<NU, 256, 0, stream>>>(loc, cord, tw, partial);
    regloss_final_kernel<<<1, 256, 0, stream>>>(partial, out);
}